// Round 1
// baseline (188.189 us; speedup 1.0000x reference)
//
#include <hip/hip_runtime.h>
#include <math.h>

// Problem constants (also derived from in_sizes at launch)
#define HEADS 4
#define CH 64
#define HC 256
#define NEG 0.2f

// Workspace caps (expected: deg(N-1)~17, |S1|~18, e1~300 — huge margins)
#define CAP_E2 256     // edges into node N-1 (incl appended self loop)
#define CAP_U  2048    // unique S1 nodes
#define CAP_E1 65536   // edges into S1 (incl appended self loops)
#define MAXD   48      // per-block local in-degree cap (layer 0)
#define MAXD2  40      // layer-1 edge cap

__device__ __forceinline__ float wave_sum64(float v) {
    #pragma unroll
    for (int off = 32; off; off >>= 1) v += __shfl_down(v, off, 64);
    return v;  // valid in lane 0
}

// ---------------- kernel 1: find edges (src -> N-1), build S1 claim map ----
__global__ void k_scan_last(const int* __restrict__ ei, int E, int N,
                            int* __restrict__ cnt, int* __restrict__ e2_src,
                            int* __restrict__ uniq, int* __restrict__ pos) {
    int e = blockIdx.x * blockDim.x + threadIdx.x;
    if (e < E) {
        int d = ei[E + e];
        if (d == N - 1) {
            int s = ei[e];
            int j = atomicAdd(&cnt[0], 1);
            if (j < CAP_E2) e2_src[j] = s;
            if (atomicCAS(&pos[s], -1, -2) == -1) {
                int u = atomicAdd(&cnt[1], 1);
                if (u < CAP_U) { uniq[u] = s; pos[s] = u; } else pos[s] = 0;
            }
        }
    }
    if (e == 0) {  // appended self loop for node N-1
        int j = atomicAdd(&cnt[0], 1);
        if (j < CAP_E2) e2_src[j] = N - 1;
        if (atomicCAS(&pos[N - 1], -1, -2) == -1) {
            int u = atomicAdd(&cnt[1], 1);
            if (u < CAP_U) { uniq[u] = N - 1; pos[N - 1] = u; } else pos[N - 1] = 0;
        }
    }
}

// ---------------- kernel 2: collect edges with dst in S1 ----------------
__global__ void k_scan_s1(const int* __restrict__ ei, int E,
                          const int* __restrict__ pos, int* __restrict__ cnt,
                          int* __restrict__ e1s, int* __restrict__ e1d) {
    int e = blockIdx.x * blockDim.x + threadIdx.x;
    if (e >= E) return;
    int d = ei[E + e];
    if (pos[d] >= 0) {
        int j = atomicAdd(&cnt[2], 1);
        if (j < CAP_E1) { e1s[j] = ei[e]; e1d[j] = d; }
    }
}

// ---------------- kernel 2b: append self loops for each S1 node ----------
__global__ void k_self(const int* __restrict__ uniq, int* __restrict__ cnt,
                       int* __restrict__ e1s, int* __restrict__ e1d) {
    int u = min(cnt[1], CAP_U);
    int i = blockIdx.x * blockDim.x + threadIdx.x;
    if (i < u) {
        int n = uniq[i];
        int j = atomicAdd(&cnt[2], 1);
        if (j < CAP_E1) { e1s[j] = n; e1d[j] = n; }
    }
}

// ---------------- kernel 3: layer-0 GAT output for each S1 node ----------
__global__ __launch_bounds__(256) void k_layer0(
    const int* __restrict__ y, const float* __restrict__ emb,
    const float* __restrict__ W0, const float* __restrict__ a_src,
    const float* __restrict__ a_dst, const float* __restrict__ bias,
    const int* __restrict__ cnt, const int* __restrict__ uniq,
    const int* __restrict__ e1s, const int* __restrict__ e1d,
    float* __restrict__ x1c)
{
    __shared__ float hrows[MAXD][HC];   // 48KB
    __shared__ float xrows[8][CH];      // 2KB
    __shared__ int locsrc[MAXD];
    __shared__ int nloc_s, jself_s;
    __shared__ float al_d_sh[HEADS], red[HEADS];
    __shared__ float earr[MAXD][HEADS];

    int ucnt = min(cnt[1], CAP_U);
    int b = blockIdx.x;
    if (b >= ucnt) return;
    int d = uniq[b];
    int tid = threadIdx.x, wave = tid >> 6, lane = tid & 63;

    if (tid == 0) { nloc_s = 0; jself_s = 0; }
    __syncthreads();
    int ce1 = min(cnt[2], CAP_E1);
    for (int i = tid; i < ce1; i += 256)
        if (e1d[i] == d) {
            int s = atomicAdd(&nloc_s, 1);
            if (s < MAXD) locsrc[s] = e1s[i];
        }
    __syncthreads();
    int nloc = min(nloc_s, MAXD);
    if (tid == 0) {
        for (int j = 0; j < nloc; ++j) if (locsrc[j] == d) { jself_s = j; break; }
    }
    __syncthreads();
    int jself = jself_s;

    // h0 rows for all local edges, register-blocked 8 edges per W0 sweep
    for (int base = 0; base < nloc; base += 8) {
        int cmax = min(8, nloc - base);
        __syncthreads();
        for (int i = tid; i < 8 * CH; i += 256) {
            int c = i >> 6, k = i & 63;
            xrows[c][k] = (c < cmax) ? emb[(long)y[locsrc[base + c]] * CH + k] : 0.f;
        }
        __syncthreads();
        float acc[8] = {0.f, 0.f, 0.f, 0.f, 0.f, 0.f, 0.f, 0.f};
        for (int k = 0; k < CH; ++k) {
            float w = W0[k * HC + tid];
            #pragma unroll
            for (int c = 0; c < 8; ++c) acc[c] = fmaf(xrows[c][k], w, acc[c]);
        }
        for (int c = 0; c < cmax; ++c) hrows[base + c][tid] = acc[c];
    }
    __syncthreads();

    float asv = a_src[tid], adv = a_dst[tid];
    {
        float s = wave_sum64(hrows[jself][tid] * adv);
        if (lane == 0) al_d_sh[wave] = s;
    }
    __syncthreads();
    for (int j = 0; j < nloc; ++j) {
        float r = wave_sum64(hrows[j][tid] * asv);
        if (lane == 0) {
            float e = r + al_d_sh[wave];
            earr[j][wave] = (e >= 0.f) ? e : NEG * e;
        }
    }
    __syncthreads();
    if (tid < HEADS) {  // per-head softmax over local edges
        float m = -1e30f;
        for (int j = 0; j < nloc; ++j) m = fmaxf(m, earr[j][tid]);
        float den = 0.f;
        for (int j = 0; j < nloc; ++j) { float w = __expf(0.f); w = expf(earr[j][tid] - m); earr[j][tid] = w; den += w; }
        float inv = 1.f / (den + 1e-16f);
        for (int j = 0; j < nloc; ++j) earr[j][tid] *= inv;
    }
    __syncthreads();
    float acc = 0.f;
    for (int j = 0; j < nloc; ++j) acc = fmaf(earr[j][wave], hrows[j][tid], acc);
    float o = acc + bias[tid];
    o = (o > 0.f) ? o : expm1f(o);
    float ss = wave_sum64(o * o);
    if (lane == 0) red[wave] = ss;
    __syncthreads();
    float nrm = sqrtf(red[0] + red[1] + red[2] + red[3]);
    x1c[b * HC + tid] = o / fmaxf(nrm, 1e-12f);
}

// ---------------- kernel 4: layer-1 GAT at node N-1 + ctx MLP ------------
__global__ __launch_bounds__(256) void k_layer1(
    const float* __restrict__ W1, const float* __restrict__ a_src,
    const float* __restrict__ a_dst, const float* __restrict__ bias,
    const float* __restrict__ pw1, const float* __restrict__ pb1,
    const int* __restrict__ cnt, const int* __restrict__ e2_src,
    const int* __restrict__ pos, const float* __restrict__ x1c,
    float* __restrict__ hidden, int N)
{
    __shared__ float hrows[MAXD2][HC];  // 40KB
    __shared__ float xrows[8][HC];      // 8KB
    __shared__ float al_d_sh[HEADS], red[HEADS];
    __shared__ float earr[MAXD2][HEADS];
    __shared__ int jself_s;

    int tid = threadIdx.x, wave = tid >> 6, lane = tid & 63;
    int ne = min(cnt[0], MAXD2);
    if (tid == 0) {
        jself_s = 0;
        for (int j = 0; j < ne; ++j) if (e2_src[j] == N - 1) { jself_s = j; break; }
    }
    __syncthreads();
    int jself = jself_s;

    for (int base = 0; base < ne; base += 8) {
        int cmax = min(8, ne - base);
        __syncthreads();
        for (int i = tid; i < 8 * HC; i += 256) {
            int c = i >> 8, t = i & 255;
            float v = 0.f;
            if (c < cmax) {
                int p = pos[e2_src[base + c]];
                if (p < 0) p = 0;
                v = x1c[p * HC + t];
            }
            xrows[c][t] = v;
        }
        __syncthreads();
        float acc[8] = {0.f, 0.f, 0.f, 0.f, 0.f, 0.f, 0.f, 0.f};
        for (int k = 0; k < HC; ++k) {
            float w = W1[k * HC + tid];
            #pragma unroll
            for (int c = 0; c < 8; ++c) acc[c] = fmaf(xrows[c][k], w, acc[c]);
        }
        for (int c = 0; c < cmax; ++c) hrows[base + c][tid] = acc[c];
    }
    __syncthreads();

    float asv = a_src[tid], adv = a_dst[tid];
    {
        float s = wave_sum64(hrows[jself][tid] * adv);
        if (lane == 0) al_d_sh[wave] = s;
    }
    __syncthreads();
    for (int j = 0; j < ne; ++j) {
        float r = wave_sum64(hrows[j][tid] * asv);
        if (lane == 0) {
            float e = r + al_d_sh[wave];
            earr[j][wave] = (e >= 0.f) ? e : NEG * e;
        }
    }
    __syncthreads();
    if (tid < HEADS) {
        float m = -1e30f;
        for (int j = 0; j < ne; ++j) m = fmaxf(m, earr[j][tid]);
        float den = 0.f;
        for (int j = 0; j < ne; ++j) { float w = expf(earr[j][tid] - m); earr[j][tid] = w; den += w; }
        float inv = 1.f / (den + 1e-16f);
        for (int j = 0; j < ne; ++j) earr[j][tid] *= inv;
    }
    __syncthreads();
    float acc = 0.f;
    for (int j = 0; j < ne; ++j) acc = fmaf(earr[j][wave], hrows[j][tid], acc);
    float o = acc + bias[tid];
    o = (o > 0.f) ? o : expm1f(o);
    float ss = wave_sum64(o * o);
    if (lane == 0) red[wave] = ss;
    __syncthreads();
    float nrm = sqrtf(red[0] + red[1] + red[2] + red[3]);
    float ctxv = o / fmaxf(nrm, 1e-12f);

    // ctx @ pw1 + pb1, relu -> hidden[64]
    __syncthreads();
    xrows[0][tid] = ctxv;
    __syncthreads();
    if (tid < 64) {
        float hv = pb1[tid];
        #pragma unroll 8
        for (int k = 0; k < HC; ++k) hv = fmaf(xrows[0][k], pw1[k * 64 + tid], hv);
        hidden[tid] = fmaxf(hv, 0.f);
    }
}

// ---------------- kernel 5: out = hidden @ pw2 + pb2 ---------------------
__global__ __launch_bounds__(256) void k_out(
    const float* __restrict__ hidden, const float* __restrict__ pw2,
    const float* __restrict__ pb2, float* __restrict__ out, int V)
{
    __shared__ float h_sh[64];
    int tid = threadIdx.x;
    if (tid < 64) h_sh[tid] = hidden[tid];
    __syncthreads();
    int v0 = (blockIdx.x * 256 + tid) * 4;
    if (v0 >= V) return;
    float4 acc = *(const float4*)(pb2 + v0);
    #pragma unroll 8
    for (int k = 0; k < 64; ++k) {
        float hk = h_sh[k];
        float4 w = *(const float4*)(pw2 + (size_t)k * V + v0);
        acc.x = fmaf(hk, w.x, acc.x);
        acc.y = fmaf(hk, w.y, acc.y);
        acc.z = fmaf(hk, w.z, acc.z);
        acc.w = fmaf(hk, w.w, acc.w);
    }
    *(float4*)(out + v0) = acc;
}

extern "C" void kernel_launch(void* const* d_in, const int* in_sizes, int n_in,
                              void* d_out, int out_size, void* d_ws, size_t ws_size,
                              hipStream_t stream) {
    const int*   y      = (const int*)d_in[0];
    const int*   ei     = (const int*)d_in[1];
    const float* emb    = (const float*)d_in[2];
    const float* W0     = (const float*)d_in[3];
    const float* a_src0 = (const float*)d_in[4];
    const float* a_dst0 = (const float*)d_in[5];
    const float* b0     = (const float*)d_in[6];
    const float* W1     = (const float*)d_in[7];
    const float* a_src1 = (const float*)d_in[8];
    const float* a_dst1 = (const float*)d_in[9];
    const float* b1     = (const float*)d_in[10];
    const float* pw1    = (const float*)d_in[11];
    const float* pb1    = (const float*)d_in[12];
    const float* pw2    = (const float*)d_in[13];
    const float* pb2    = (const float*)d_in[14];
    int N = in_sizes[0];
    int E = in_sizes[1] / 2;
    int V = in_sizes[14];
    float* out = (float*)d_out;

    // carve workspace (bump allocator, 256B aligned)
    char* p = (char*)d_ws;
    auto alloc = [&](size_t bytes) {
        char* r = p;
        p += (bytes + 255) & ~(size_t)255;
        return r;
    };
    int*   cnt    = (int*)alloc(64);                       // [0]=e2 cnt [1]=ucnt [2]=e1 cnt
    float* hidden = (float*)alloc(64 * sizeof(float));
    int*   e2     = (int*)alloc(CAP_E2 * sizeof(int));
    int*   uniq   = (int*)alloc(CAP_U * sizeof(int));
    int*   e1s    = (int*)alloc(CAP_E1 * sizeof(int));
    int*   e1d    = (int*)alloc(CAP_E1 * sizeof(int));
    int*   pos    = (int*)alloc((size_t)N * sizeof(int));
    float* x1c    = (float*)alloc((size_t)CAP_U * HC * sizeof(float));

    hipMemsetAsync(cnt, 0, 64, stream);
    hipMemsetAsync(pos, 0xFF, (size_t)N * sizeof(int), stream);  // pos = -1

    int blocksE = (E + 255) / 256;
    k_scan_last<<<blocksE, 256, 0, stream>>>(ei, E, N, cnt, e2, uniq, pos);
    k_scan_s1<<<blocksE, 256, 0, stream>>>(ei, E, pos, cnt, e1s, e1d);
    k_self<<<(CAP_U + 255) / 256, 256, 0, stream>>>(uniq, cnt, e1s, e1d);
    k_layer0<<<CAP_U, 256, 0, stream>>>(y, emb, W0, a_src0, a_dst0, b0,
                                        cnt, uniq, e1s, e1d, x1c);
    k_layer1<<<1, 256, 0, stream>>>(W1, a_src1, a_dst1, b1, pw1, pb1,
                                    cnt, e2, pos, x1c, hidden, N);
    k_out<<<(V + 1023) / 1024, 256, 0, stream>>>(hidden, pw2, pb2, out, V);
}

// Round 2
// 155.311 us; speedup vs baseline: 1.2117x; 1.2117x over previous
//
#include <hip/hip_runtime.h>
#include <math.h>

#define HEADS 4
#define CH 64
#define HC 256
#define NEG 0.2f

// caps (expected: deg(N-1)~17, |S1|~18, e1~340)
#define CAP_E2 64      // edges into node N-1 (incl appended self loop)
#define CAP_U  2048    // unique S1 nodes
#define CAP_E1 65536   // recorded edges into S1
#define H0CAP  4096    // h0 rows materialized (>=10x expected e1 count)
#define MAXD   256     // per-dst local in-degree cap (layer 0 agg)
#define MAXD2  64      // layer-1 edge cap

__device__ __forceinline__ float wave_sum64(float v) {
    #pragma unroll
    for (int off = 32; off; off >>= 1) v += __shfl_down(v, off, 64);
    return v;  // valid in lane 0
}

// ---- kernel 1: edges (src -> N-1), claim S1 membership ----
__global__ void k_scan_last(const int* __restrict__ ei, int E, int N,
                            int* __restrict__ cnt, int* __restrict__ e2_src,
                            int* __restrict__ uniq, int* __restrict__ pos) {
    int e = blockIdx.x * blockDim.x + threadIdx.x;
    if (e < E) {
        int d = ei[E + e];
        if (d == N - 1) {
            int s = ei[e];
            int j = atomicAdd(&cnt[0], 1);
            if (j < CAP_E2) e2_src[j] = s;
            if (atomicCAS(&pos[s], -1, -2) == -1) {
                int u = atomicAdd(&cnt[1], 1);
                if (u < CAP_U) { uniq[u] = s; pos[s] = u; } else pos[s] = 0;
            }
        }
    }
    if (e == 0) {  // appended self loop for node N-1
        int j = atomicAdd(&cnt[0], 1);
        if (j < CAP_E2) e2_src[j] = N - 1;
        if (atomicCAS(&pos[N - 1], -1, -2) == -1) {
            int u = atomicAdd(&cnt[1], 1);
            if (u < CAP_U) { uniq[u] = N - 1; pos[N - 1] = u; } else pos[N - 1] = 0;
        }
    }
}

// ---- kernel 2: collect edges with dst in S1 ----
__global__ void k_scan_s1(const int* __restrict__ ei, int E,
                          const int* __restrict__ pos, int* __restrict__ cnt,
                          int* __restrict__ e1s, int* __restrict__ e1d) {
    int e = blockIdx.x * blockDim.x + threadIdx.x;
    if (e >= E) return;
    int d = ei[E + e];
    if (pos[d] >= 0) {
        int j = atomicAdd(&cnt[2], 1);
        if (j < CAP_E1) { e1s[j] = ei[e]; e1d[j] = d; }
    }
}

// ---- kernel 2b: append self loop per S1 node, remember its slot ----
__global__ void k_self(const int* __restrict__ uniq, int* __restrict__ cnt,
                       int* __restrict__ e1s, int* __restrict__ e1d,
                       int* __restrict__ selfidx) {
    int u = min(cnt[1], CAP_U);
    int i = blockIdx.x * blockDim.x + threadIdx.x;
    if (i < u) {
        int n = uniq[i];
        int j = atomicAdd(&cnt[2], 1);
        if (j < CAP_E1) { e1s[j] = n; e1d[j] = n; selfidx[i] = j; }
        else selfidx[i] = 0;
    }
}

// ---- kernel 3: one block per layer-0 edge: h0 row + a_src logit ----
__global__ __launch_bounds__(256) void k_h0(
    const int* __restrict__ y, const float* __restrict__ emb,
    const float* __restrict__ W0, const float* __restrict__ a_src,
    const int* __restrict__ cnt, const int* __restrict__ e1s,
    float* __restrict__ h0, float* __restrict__ als0)
{
    __shared__ float xr[CH];
    int i = blockIdx.x;
    int ce1 = min(cnt[2], H0CAP);
    if (i >= ce1) return;
    int tid = threadIdx.x, wave = tid >> 6, lane = tid & 63;
    if (tid < CH) xr[tid] = emb[(long)y[e1s[i]] * CH + tid];
    __syncthreads();
    float acc = 0.f;
    #pragma unroll
    for (int k = 0; k < CH; ++k) acc = fmaf(xr[k], W0[k * HC + tid], acc);
    h0[(long)i * HC + tid] = acc;
    float r = wave_sum64(acc * a_src[tid]);
    if (lane == 0) als0[i * HEADS + wave] = r;
}

// ---- kernel 4: one block per S1 node: attention + aggregate + elu + norm ----
__global__ __launch_bounds__(256) void k_agg0(
    const float* __restrict__ a_dst, const float* __restrict__ bias,
    const int* __restrict__ cnt, const int* __restrict__ uniq,
    const int* __restrict__ e1d, const int* __restrict__ selfidx,
    const float* __restrict__ h0, const float* __restrict__ als0,
    float* __restrict__ x1c)
{
    __shared__ int gidx[MAXD];
    __shared__ int nloc_s;
    __shared__ float al_d_sh[HEADS];
    __shared__ float earr[MAXD][HEADS];
    __shared__ float red[HEADS];

    int ucnt = min(cnt[1], CAP_U);
    int b = blockIdx.x;
    if (b >= ucnt) return;
    int d = uniq[b];
    int tid = threadIdx.x, wave = tid >> 6, lane = tid & 63;

    if (tid == 0) nloc_s = 0;
    __syncthreads();
    int ce1 = min(cnt[2], H0CAP);
    for (int i = tid; i < ce1; i += 256)
        if (e1d[i] == d) {
            int s = atomicAdd(&nloc_s, 1);
            if (s < MAXD) gidx[s] = i;
        }
    __syncthreads();
    int nloc = min(nloc_s, MAXD);

    // al_dst from the self-loop row (h of node d itself)
    int gs = selfidx[b];
    {
        float r = wave_sum64(h0[(long)gs * HC + tid] * a_dst[tid]);
        if (lane == 0) al_d_sh[wave] = r;
    }
    __syncthreads();
    for (int idx = tid; idx < nloc * HEADS; idx += 256) {
        int j = idx >> 2, h = idx & 3;
        float e = als0[gidx[j] * HEADS + h] + al_d_sh[h];
        earr[j][h] = (e >= 0.f) ? e : NEG * e;
    }
    __syncthreads();
    if (tid < HEADS) {
        float m = -1e30f;
        for (int j = 0; j < nloc; ++j) m = fmaxf(m, earr[j][tid]);
        float den = 0.f;
        for (int j = 0; j < nloc; ++j) { float w = expf(earr[j][tid] - m); earr[j][tid] = w; den += w; }
        float inv = 1.f / (den + 1e-16f);
        for (int j = 0; j < nloc; ++j) earr[j][tid] *= inv;
    }
    __syncthreads();
    float acc = 0.f;
    for (int j = 0; j < nloc; ++j)
        acc = fmaf(earr[j][wave], h0[(long)gidx[j] * HC + tid], acc);
    float o = acc + bias[tid];
    o = (o > 0.f) ? o : expm1f(o);
    float ss = wave_sum64(o * o);
    if (lane == 0) red[wave] = ss;
    __syncthreads();
    float nrm = sqrtf(red[0] + red[1] + red[2] + red[3]);
    x1c[b * HC + tid] = o / fmaxf(nrm, 1e-12f);
}

// ---- kernel 5: one block per layer-1 edge: h1 row + a_src logit ----
__global__ __launch_bounds__(256) void k_h1(
    const float* __restrict__ W1, const float* __restrict__ a_src,
    const int* __restrict__ cnt, const int* __restrict__ e2_src,
    const int* __restrict__ pos, const float* __restrict__ x1c,
    float* __restrict__ h1, float* __restrict__ als1)
{
    __shared__ float xr[HC];
    int j = blockIdx.x;
    int ne = min(cnt[0], MAXD2);
    if (j >= ne) return;
    int tid = threadIdx.x, wave = tid >> 6, lane = tid & 63;
    int p = pos[e2_src[j]];
    if (p < 0) p = 0;
    xr[tid] = x1c[p * HC + tid];
    __syncthreads();
    float acc = 0.f;
    #pragma unroll 16
    for (int k = 0; k < HC; ++k) acc = fmaf(xr[k], W1[k * HC + tid], acc);
    h1[j * HC + tid] = acc;
    float r = wave_sum64(acc * a_src[tid]);
    if (lane == 0) als1[j * HEADS + wave] = r;
}

// ---- kernel 6: attention at N-1 + ctx MLP (hidden = relu(ctx@pw1+pb1)) ----
__global__ __launch_bounds__(256) void k_final(
    const float* __restrict__ a_dst, const float* __restrict__ bias,
    const float* __restrict__ pw1, const float* __restrict__ pb1,
    const int* __restrict__ cnt, const int* __restrict__ e2_src,
    const float* __restrict__ h1, const float* __restrict__ als1,
    float* __restrict__ hidden, int N)
{
    __shared__ float al_d_sh[HEADS], red[HEADS];
    __shared__ float earr[MAXD2][HEADS];
    __shared__ float ctx_sh[HC];
    __shared__ float part[HEADS][CH];
    __shared__ int jself_s;

    int tid = threadIdx.x, wave = tid >> 6, lane = tid & 63;
    int ne = min(cnt[0], MAXD2);
    if (tid == 0) {
        jself_s = 0;
        for (int j = 0; j < ne; ++j) if (e2_src[j] == N - 1) { jself_s = j; break; }
    }
    __syncthreads();
    int jself = jself_s;
    {
        float r = wave_sum64(h1[jself * HC + tid] * a_dst[tid]);
        if (lane == 0) al_d_sh[wave] = r;
    }
    __syncthreads();
    for (int idx = tid; idx < ne * HEADS; idx += 256) {
        int j = idx >> 2, h = idx & 3;
        float e = als1[j * HEADS + h] + al_d_sh[h];
        earr[j][h] = (e >= 0.f) ? e : NEG * e;
    }
    __syncthreads();
    if (tid < HEADS) {
        float m = -1e30f;
        for (int j = 0; j < ne; ++j) m = fmaxf(m, earr[j][tid]);
        float den = 0.f;
        for (int j = 0; j < ne; ++j) { float w = expf(earr[j][tid] - m); earr[j][tid] = w; den += w; }
        float inv = 1.f / (den + 1e-16f);
        for (int j = 0; j < ne; ++j) earr[j][tid] *= inv;
    }
    __syncthreads();
    float acc = 0.f;
    for (int j = 0; j < ne; ++j)
        acc = fmaf(earr[j][wave], h1[j * HC + tid], acc);
    float o = acc + bias[tid];
    o = (o > 0.f) ? o : expm1f(o);
    float ss = wave_sum64(o * o);
    if (lane == 0) red[wave] = ss;
    __syncthreads();
    float nrm = sqrtf(red[0] + red[1] + red[2] + red[3]);
    ctx_sh[tid] = o / fmaxf(nrm, 1e-12f);
    __syncthreads();

    // hidden = relu(ctx @ pw1 + pb1); split K across the 4 waves
    int col = tid & 63;
    float hv = 0.f;
    #pragma unroll 16
    for (int k = wave * 64; k < wave * 64 + 64; ++k)
        hv = fmaf(ctx_sh[k], pw1[k * CH + col], hv);
    part[wave][col] = hv;
    __syncthreads();
    if (tid < CH) {
        float v = part[0][tid] + part[1][tid] + part[2][tid] + part[3][tid] + pb1[tid];
        hidden[tid] = fmaxf(v, 0.f);
    }
}

// ---- kernel 7: out = hidden @ pw2 + pb2 ----
__global__ __launch_bounds__(256) void k_out(
    const float* __restrict__ hidden, const float* __restrict__ pw2,
    const float* __restrict__ pb2, float* __restrict__ out, int V)
{
    __shared__ float h_sh[CH];
    int tid = threadIdx.x;
    if (tid < CH) h_sh[tid] = hidden[tid];
    __syncthreads();
    int v0 = (blockIdx.x * 256 + tid) * 4;
    if (v0 >= V) return;
    float4 acc = *(const float4*)(pb2 + v0);
    #pragma unroll 8
    for (int k = 0; k < CH; ++k) {
        float hk = h_sh[k];
        float4 w = *(const float4*)(pw2 + (size_t)k * V + v0);
        acc.x = fmaf(hk, w.x, acc.x);
        acc.y = fmaf(hk, w.y, acc.y);
        acc.z = fmaf(hk, w.z, acc.z);
        acc.w = fmaf(hk, w.w, acc.w);
    }
    *(float4*)(out + v0) = acc;
}

extern "C" void kernel_launch(void* const* d_in, const int* in_sizes, int n_in,
                              void* d_out, int out_size, void* d_ws, size_t ws_size,
                              hipStream_t stream) {
    const int*   y      = (const int*)d_in[0];
    const int*   ei     = (const int*)d_in[1];
    const float* emb    = (const float*)d_in[2];
    const float* W0     = (const float*)d_in[3];
    const float* a_src0 = (const float*)d_in[4];
    const float* a_dst0 = (const float*)d_in[5];
    const float* b0     = (const float*)d_in[6];
    const float* W1     = (const float*)d_in[7];
    const float* a_src1 = (const float*)d_in[8];
    const float* a_dst1 = (const float*)d_in[9];
    const float* b1     = (const float*)d_in[10];
    const float* pw1    = (const float*)d_in[11];
    const float* pb1    = (const float*)d_in[12];
    const float* pw2    = (const float*)d_in[13];
    const float* pb2    = (const float*)d_in[14];
    int N = in_sizes[0];
    int E = in_sizes[1] / 2;
    int V = in_sizes[14];
    float* out = (float*)d_out;

    char* p = (char*)d_ws;
    auto alloc = [&](size_t bytes) {
        char* r = p;
        p += (bytes + 255) & ~(size_t)255;
        return r;
    };
    int*   cnt     = (int*)alloc(64);            // [0]=e2 [1]=ucnt [2]=e1
    float* hidden  = (float*)alloc(CH * sizeof(float));
    int*   e2      = (int*)alloc(CAP_E2 * sizeof(int));
    int*   uniq    = (int*)alloc(CAP_U * sizeof(int));
    int*   selfidx = (int*)alloc(CAP_U * sizeof(int));
    int*   e1s     = (int*)alloc(CAP_E1 * sizeof(int));
    int*   e1d     = (int*)alloc(CAP_E1 * sizeof(int));
    int*   pos     = (int*)alloc((size_t)N * sizeof(int));
    float* x1c     = (float*)alloc((size_t)CAP_U * HC * sizeof(float));
    float* als0    = (float*)alloc((size_t)H0CAP * HEADS * sizeof(float));
    float* h0      = (float*)alloc((size_t)H0CAP * HC * sizeof(float));
    float* als1    = (float*)alloc((size_t)MAXD2 * HEADS * sizeof(float));
    float* h1      = (float*)alloc((size_t)MAXD2 * HC * sizeof(float));

    hipMemsetAsync(cnt, 0, 64, stream);
    hipMemsetAsync(pos, 0xFF, (size_t)N * sizeof(int), stream);

    int blocksE = (E + 255) / 256;
    k_scan_last<<<blocksE, 256, 0, stream>>>(ei, E, N, cnt, e2, uniq, pos);
    k_scan_s1<<<blocksE, 256, 0, stream>>>(ei, E, pos, cnt, e1s, e1d);
    k_self<<<(CAP_U + 255) / 256, 256, 0, stream>>>(uniq, cnt, e1s, e1d, selfidx);
    k_h0<<<H0CAP, 256, 0, stream>>>(y, emb, W0, a_src0, cnt, e1s, h0, als0);
    k_agg0<<<CAP_U, 256, 0, stream>>>(a_dst0, b0, cnt, uniq, e1d, selfidx, h0, als0, x1c);
    k_h1<<<MAXD2, 256, 0, stream>>>(W1, a_src1, cnt, e2, pos, x1c, h1, als1);
    k_final<<<1, 256, 0, stream>>>(a_dst1, b1, pw1, pb1, cnt, e2, h1, als1, hidden, N);
    k_out<<<(V + 1023) / 1024, 256, 0, stream>>>(hidden, pw2, pb2, out, V);
}